// Round 18
// baseline (106.131 us; speedup 1.0000x reference)
//
#include <hip/hip_runtime.h>

typedef unsigned short u16;
typedef unsigned int u32;
typedef __attribute__((ext_vector_type(8))) __bf16 bf16x8;
typedef __attribute__((ext_vector_type(4))) float f32x4;
typedef __attribute__((ext_vector_type(16))) float f32x16;
typedef __attribute__((ext_vector_type(4))) u32 u32x4;

#define LOG2E 1.44269504088896340736f

__device__ __forceinline__ u16 f2bf(float f) {
  u32 u = __builtin_bit_cast(u32, f);
  u += 0x7fffu + ((u >> 16) & 1u);
  return (u16)(u >> 16);
}

__device__ __forceinline__ void async_copy16(const u16* g, u16* l) {
  __builtin_amdgcn_global_load_lds((const __attribute__((address_space(1))) void*)g,
                                   (__attribute__((address_space(3))) void*)l,
                                   16, 0, 0);
}

__device__ __forceinline__ bf16x8 ldb8(const u16* p) {
  return *(const bf16x8*)p;
}

__device__ __forceinline__ u32 cvtpk(float lo, float hi) {
  u32 w;
  asm("v_cvt_pk_bf16_f32 %0, %1, %2" : "=v"(w) : "v"(lo), "v"(hi));
  return w;
}

// ---------------------------------------------------------------------------
// Kernel 1: fused f32 -> bf16 conversion (memory floor ~15 µs).
// ---------------------------------------------------------------------------
__global__ __launch_bounds__(256) void convert_kernel(
    const float* __restrict__ q, const float* __restrict__ k, const float* __restrict__ v,
    const float* __restrict__ wq, const float* __restrict__ wk,
    const float* __restrict__ wv, const float* __restrict__ wo,
    u16* __restrict__ out)
{
  size_t t = (size_t)blockIdx.x * 256 + threadIdx.x;  // 0 .. 2M-1
  size_t e = t * 8;
  const float* src;
  size_t off;
  if (e < 12582912) {            // 3 x 4M qkv region
    int which = (int)(e >> 22);
    src = (which == 0) ? q : ((which == 1) ? k : v);
    off = e & 4194303;
  } else {                        // 4 x 1M weight region
    size_t r = e - 12582912;
    int which = (int)(r >> 20);
    src = (which == 0) ? wq : ((which == 1) ? wk : ((which == 2) ? wv : wo));
    off = r & 1048575;
  }
  float4 f0 = *(const float4*)(src + off);
  float4 f1 = *(const float4*)(src + off + 4);
  ushort4 u0, u1;
  u0.x = f2bf(f0.x); u0.y = f2bf(f0.y); u0.z = f2bf(f0.z); u0.w = f2bf(f0.w);
  u1.x = f2bf(f1.x); u1.y = f2bf(f1.y); u1.z = f2bf(f1.z); u1.w = f2bf(f1.w);
  *(ushort4*)(out + e) = u0;
  *(ushort4*)(out + e + 4) = u1;
}

// ---------------------------------------------------------------------------
// R16 GEMM core (kept): 128x128 block, 8 waves (2x4), wave tile 64x32, BK=64,
// 64 KB LDS -> 2 blocks/CU, 16 waves/CU. 16x16x32 MFMA, 0-conflict swizzle
// (slot=cc^(row&7), pre-swizzled DMA source + same XOR on ds_read), T3
// schedule (STAGE(t+1) top, compute, __syncthreads bottom).
// ---------------------------------------------------------------------------
template <int MODE>
__device__ __forceinline__ void gemm128x128w8(
    const u16* __restrict__ A, const u16* __restrict__ W,
    const float* __restrict__ bias, void* __restrict__ out,
    float scale, u16* As, u16* Bs)
{
  const int tid = threadIdx.x;
  const int wid = tid >> 6, lane = tid & 63;
  const int g = lane >> 4, l16 = lane & 15;
  const int wr = wid >> 2, wc = wid & 3;          // 2 x 4 wave grid
  const int brow = blockIdx.x * 128, bcol = blockIdx.y * 128;

  f32x4 acc[4][2] = {};
  const u16* Ab = A + (size_t)brow * 1024;
  const u16* Wb = W + (size_t)bcol * 1024;

  auto STAGE = [&](int buf, int kt2) {
    const int k0 = kt2 * 64;
    u16* Ad = As + buf * 8192;
    u16* Bd = Bs + buf * 8192;
#pragma unroll
    for (int i = 0; i < 2; ++i) {
      const int chunk = i * 512 + tid;
      const int row = chunk >> 3, cc = chunk & 7;
      const int sc = (cc ^ (row & 7)) * 8;
      const int lbase = (i * 512 + wid * 64) * 8;  // elems; HW adds lane*16B
      async_copy16(Ab + (size_t)row * 1024 + k0 + sc, Ad + lbase);
      async_copy16(Wb + (size_t)row * 1024 + k0 + sc, Bd + lbase);
    }
  };

  STAGE(0, 0);
  __syncthreads();

  for (int kt = 0; kt < 16; ++kt) {
    if (kt < 15) STAGE((kt + 1) & 1, kt + 1);   // prefetch next tile (async)

    const u16* Ac = As + (kt & 1) * 8192;
    const u16* Bc = Bs + (kt & 1) * 8192;

    bf16x8 a[4][2], b[2][2];
#pragma unroll
    for (int m = 0; m < 4; ++m) {
      const int row = wr * 64 + m * 16 + l16;
#pragma unroll
      for (int kk = 0; kk < 2; ++kk)
        a[m][kk] = ldb8(Ac + row * 64 + (((kk * 4 + g) ^ (row & 7)) * 8));
    }
#pragma unroll
    for (int n = 0; n < 2; ++n) {
      const int row = wc * 32 + n * 16 + l16;
#pragma unroll
      for (int kk = 0; kk < 2; ++kk)
        b[n][kk] = ldb8(Bc + row * 64 + (((kk * 4 + g) ^ (row & 7)) * 8));
    }
#pragma unroll
    for (int m = 0; m < 4; ++m)
#pragma unroll
      for (int n = 0; n < 2; ++n) {
        acc[m][n] = __builtin_amdgcn_mfma_f32_16x16x32_bf16(a[m][0], b[n][0], acc[m][n], 0, 0, 0);
        acc[m][n] = __builtin_amdgcn_mfma_f32_16x16x32_bf16(a[m][1], b[n][1], acc[m][n], 0, 0, 0);
      }

    __syncthreads();
  }

  // epilogue
#pragma unroll
  for (int m = 0; m < 4; ++m) {
    const int mg = brow + wr * 64 + m * 16 + g * 4;  // + j
#pragma unroll
    for (int n = 0; n < 2; ++n) {
      const int cg = bcol + wc * 32 + n * 16 + l16;
      const float bb = bias[cg];
      if constexpr (MODE == 0) {
        const int h = cg >> 6, d = cg & 63;
#pragma unroll
        for (int j = 0; j < 4; ++j) {
          const int row = mg + j;
          const int bb_ = row >> 11, s = row & 2047;
          ((u16*)out)[(((size_t)(bb_ * 16 + h) * 2048 + s) << 6) + d] =
              f2bf((acc[m][n][j] + bb) * scale);
        }
      } else if constexpr (MODE == 1) {
        const int h = cg >> 6, d = cg & 63;
        const int bb_ = mg >> 11, s0 = mg & 2047;
        ushort4 pk;
        pk.x = f2bf(acc[m][n][0] + bb);
        pk.y = f2bf(acc[m][n][1] + bb);
        pk.z = f2bf(acc[m][n][2] + bb);
        pk.w = f2bf(acc[m][n][3] + bb);
        *(ushort4*)((u16*)out + ((size_t)(bb_ * 16 + h) * 64 + d) * 2048 + s0) = pk;
      } else {
#pragma unroll
        for (int j = 0; j < 4; ++j) {
          const int row = mg + j;
          ((float*)out)[(size_t)row * 1024 + cg] = acc[m][n][j] + bb;
        }
      }
    }
  }
}

__global__ __launch_bounds__(512) void qkv_gemm_kernel(
    const u16* __restrict__ xq, const u16* __restrict__ xk, const u16* __restrict__ xv,
    const u16* __restrict__ wq, const u16* __restrict__ wk, const u16* __restrict__ wv,
    const float* __restrict__ bq, const float* __restrict__ bk, const float* __restrict__ bv,
    u16* __restrict__ oq, u16* __restrict__ ok, u16* __restrict__ ov)
{
  __shared__ u16 As[2][8192];
  __shared__ u16 Bs[2][8192];
  const int z = blockIdx.z;
  // Q pre-scaled by 1/sqrt(64) * log2(e): attention then uses p = exp2(s) directly.
  if (z == 0)      gemm128x128w8<0>(xq, wq, bq, oq, 0.125f * LOG2E, &As[0][0], &Bs[0][0]);
  else if (z == 1) gemm128x128w8<0>(xk, wk, bk, ok, 1.0f, &As[0][0], &Bs[0][0]);    // K
  else             gemm128x128w8<1>(xv, wv, bv, ov, 1.0f, &As[0][0], &Bs[0][0]);    // V transposed
}

__global__ __launch_bounds__(512) void out_gemm_kernel(
    const u16* __restrict__ a, const u16* __restrict__ w,
    const float* __restrict__ bias, float* __restrict__ o)
{
  __shared__ u16 As[2][8192];
  __shared__ u16 Bs[2][8192];
  gemm128x128w8<2>(a, w, bias, o, 1.0f, &As[0][0], &Bs[0][0]);
}

// ---------------------------------------------------------------------------
// Kernel 3 (R18): flash attention, 2 q-sets per wave (R17's proven ILP) but
// FOUR-wave blocks (256 threads = 2 q-owners x 2 KV-parity groups) and grid
// 512 -> exactly 2 blocks/CU: when one block sits at __syncthreads, the
// other block's waves compute (the cross-block overlap R17's 1-block/CU grid
// could not have; same mechanism that makes the qkv GEMM fast). Per-wave
// work identical to R17: 64 q-rows, K/V frags shared across the two q-sets,
// 40 MFMA/round in 2 independent chains. Fixed-max softmax -> exact additive
// combine across parity (single publish barrier, 48 KB of partials in SB).
// LDS 64 KB: SB[0..3]=K tile bufs, SB[4..7]=V tile bufs (8 KB each).
// XCD remap: 512 blocks -> each XCD owns 4 whole heads.
// ---------------------------------------------------------------------------
__global__ __launch_bounds__(256, 2) void attn_kernel(
    const u16* __restrict__ qp, const u16* __restrict__ kp,
    const u16* __restrict__ vt, u16* __restrict__ ao)
{
  __shared__ u16 SB[8][4096];   // 64 KB

  const int tid = threadIdx.x;
  const int wid = tid >> 6, lane = tid & 63;
  const int u = lane >> 5, l32 = lane & 31;
  const int wsub = wid & 1, g2 = wid >> 1;   // q-owner (2) / KV parity group (2)

  // XCD-chunked remap: 512 blocks, 8 XCDs -> each XCD owns 4 whole heads.
  int bid = (int)blockIdx.x;
  bid = (bid & 7) * 64 + (bid >> 3);
  const int bh = bid >> 4;                   // b*16 + h
  const int q0 = (bid & 15) * 128 + wsub * 64;

  const u16* Q = qp + ((size_t)bh * 2048 + q0) * 64;
  const u16* K = kp + (size_t)bh * 2048 * 64;
  const u16* V = vt + (size_t)bh * 64 * 2048;

  // Q as B-fragments, two q-sets: col = q = qs*32 + l32
  bf16x8 aq[2][4];
#pragma unroll
  for (int qs = 0; qs < 2; ++qs)
#pragma unroll
    for (int st = 0; st < 4; ++st)
      aq[qs][st] = ldb8(Q + (qs * 32 + l32) * 64 + st * 16 + u * 8);

  f32x16 outa[2][2] = {};   // [qs][nb] C[q_row][d=nb*32+l32]
  f32x16 outsum[2] = {};    // [qs] running row-sum (denominator)
  f32x16 zf16 = {};

  const __bf16 one_bf = (__bf16)1.0f;
  bf16x8 ones = {one_bf, one_bf, one_bf, one_bf, one_bf, one_bf, one_bf, one_bf};

  // stage ONE tile (256 threads, 2 K-loads + 2 V-loads per thread).
  auto STAGE1 = [&](int buf, int kb) {
#pragma unroll
    for (int i = 0; i < 2; ++i) {
      const int c = i * 256 + tid;
      const int half = c >> 8, row = (c & 255) >> 2, slot = c & 3;
      const int sc = (slot ^ ((row >> 1) & 3)) * 8;
      const int lbase = (i * 256 + wid * 64) * 8;  // elems; HW adds lane*16B
      async_copy16(K + (size_t)(kb + row) * 64 + half * 32 + sc, &SB[buf][lbase]);
      async_copy16(V + (size_t)row * 2048 + kb + half * 32 + sc, &SB[4 + buf][lbase]);
    }
  };

  STAGE1(0, 0);      // tile 0
  STAGE1(1, 64);     // tile 1

  for (int T = 0; T < 16; ++T) {
    __syncthreads();   // pair T ready (staged one full round ago); pair T+1 bufs free
    if (T < 15) {
      STAGE1((2 * T + 2) & 3, (2 * T + 2) * 64);
      STAGE1((2 * T + 3) & 3, (2 * T + 3) * 64);
    }

    const int kt = 2 * T + g2;   // group 0: even tiles, group 1: odd tiles
    const u16* Kb = &SB[kt & 3][0];
    const u16* Vb = &SB[4 + (kt & 3)][0];

    // Swapped QK^T for BOTH q-sets, sharing each K fragment.
    f32x16 s[2][2];   // [qs][half]
    __builtin_amdgcn_s_setprio(1);
#pragma unroll
    for (int half = 0; half < 2; ++half) {
      const int krow = half * 32 + l32;
#pragma unroll
      for (int st = 0; st < 4; ++st) {
        const bf16x8 kf = ldb8(Kb + (st >> 1) * 2048 + krow * 32 +
                               ((((st & 1) * 2 + u) ^ ((krow >> 1) & 3)) * 8));
        s[0][half] = __builtin_amdgcn_mfma_f32_32x32x16_bf16(
            kf, aq[0][st], (st == 0) ? zf16 : s[0][half], 0, 0, 0);
        s[1][half] = __builtin_amdgcn_mfma_f32_32x32x16_bf16(
            kf, aq[1][st], (st == 0) ? zf16 : s[1][half], 0, 0, 0);
      }
    }
    __builtin_amdgcn_s_setprio(0);

    // p = exp2(s); pack adjacent-k pairs to bf16x2 words (per q-set chain)
    u32 Wd[2][2][8];
#pragma unroll
    for (int qs = 0; qs < 2; ++qs)
#pragma unroll
      for (int half = 0; half < 2; ++half)
#pragma unroll
        for (int p = 0; p < 8; ++p) {
          const float p0 = __builtin_amdgcn_exp2f(s[qs][half][2 * p]);
          const float p1 = __builtin_amdgcn_exp2f(s[qs][half][2 * p + 1]);
          Wd[qs][half][p] = cvtpk(p0, p1);
        }

    // PV: 4 k-steps of 16; V fragment shared between the two q-set chains.
#pragma unroll
    for (int t = 0; t < 4; ++t) {
      bf16x8 paf[2];
#pragma unroll
      for (int qs = 0; qs < 2; ++qs) {
        u32 c0 = Wd[qs][t >> 1][(t & 1) * 4 + 0];
        u32 c1 = Wd[qs][t >> 1][(t & 1) * 4 + 1];
        u32 c2 = Wd[qs][t >> 1][(t & 1) * 4 + 2];
        u32 c3 = Wd[qs][t >> 1][(t & 1) * 4 + 3];
        asm volatile("v_permlane32_swap_b32 %0, %1" : "+v"(c0), "+v"(c2));
        asm volatile("v_permlane32_swap_b32 %0, %1" : "+v"(c1), "+v"(c3));
        u32x4 wv = {c0, c1, c2, c3};
        paf[qs] = __builtin_bit_cast(bf16x8, wv);
      }
      __builtin_amdgcn_s_setprio(1);
      outsum[0] = __builtin_amdgcn_mfma_f32_32x32x16_bf16(paf[0], ones, outsum[0], 0, 0, 0);
      outsum[1] = __builtin_amdgcn_mfma_f32_32x32x16_bf16(paf[1], ones, outsum[1], 0, 0, 0);
#pragma unroll
      for (int nb = 0; nb < 2; ++nb) {
        const int dv = nb * 32 + l32;
        const bf16x8 vf = ldb8(Vb + (t >> 1) * 2048 + dv * 32 +
                               ((((t & 1) * 2 + u) ^ ((dv >> 1) & 3)) * 8));
        outa[0][nb] = __builtin_amdgcn_mfma_f32_32x32x16_bf16(paf[0], vf, outa[0][nb], 0, 0, 0);
        outa[1][nb] = __builtin_amdgcn_mfma_f32_32x32x16_bf16(paf[1], vf, outa[1][nb], 0, 0, 0);
      }
      __builtin_amdgcn_s_setprio(0);
    }
  }

  // ---- exact combine across parity groups (single publish barrier) ----
  __syncthreads();                   // all compute reads done; SB reusable
  float* exA = (float*)&SB[0][0];    // 8192 floats (32 KB): outa partials
  float* exS = exA + 8192;           // 4096 floats (16 KB): outsum partials
  if (g2 == 1) {
    const int ow = wid - 2;          // owner index 0/1
#pragma unroll
    for (int qs = 0; qs < 2; ++qs) {
#pragma unroll
      for (int nb = 0; nb < 2; ++nb)
#pragma unroll
        for (int r = 0; r < 16; ++r)
          exA[((ow * 64 + qs * 32 + nb * 16 + r)) * 64 + lane] = outa[qs][nb][r];
#pragma unroll
      for (int r = 0; r < 16; ++r)
        exS[((ow * 32 + qs * 16 + r)) * 64 + lane] = outsum[qs][r];
    }
  }
  __syncthreads();
  if (g2 == 0) {
    const int ow = wid;              // owner index 0/1
    const int b = bh >> 4, h = bh & 15;
#pragma unroll
    for (int qs = 0; qs < 2; ++qs) {
#pragma unroll
      for (int r = 0; r < 16; ++r) {
        const float l = outsum[qs][r] + exS[((ow * 32 + qs * 16 + r)) * 64 + lane];
        const float inv = 1.0f / l;
        const int srow = q0 + qs * 32 + (r & 3) + 8 * (r >> 2) + 4 * u;
#pragma unroll
        for (int nb = 0; nb < 2; ++nb) {
          const float o = outa[qs][nb][r] +
                          exA[((ow * 64 + qs * 32 + nb * 16 + r)) * 64 + lane];
          ao[((size_t)b * 2048 + srow) * 1024 + h * 64 + nb * 32 + l32] =
              __builtin_bit_cast(u16, (__bf16)(o * inv));
        }
      }
    }
  }
}

// ---------------------------------------------------------------------------
extern "C" void kernel_launch(void* const* d_in, const int* in_sizes, int n_in,
                              void* d_out, int out_size, void* d_ws, size_t ws_size,
                              hipStream_t stream) {
  const float* q  = (const float*)d_in[0];
  const float* k  = (const float*)d_in[1];
  const float* v  = (const float*)d_in[2];
  const float* Wq = (const float*)d_in[3];
  const float* bq = (const float*)d_in[4];
  const float* Wk = (const float*)d_in[5];
  const float* bk = (const float*)d_in[6];
  const float* Wv = (const float*)d_in[7];
  const float* bv = (const float*)d_in[8];
  const float* Wo = (const float*)d_in[9];
  const float* bo = (const float*)d_in[10];

  u16* ws = (u16*)d_ws;
  u16* xq   = ws;                  // query bf16   (4M)
  u16* xk   = ws + 4194304;        // key bf16     (4M)
  u16* xv   = ws + 8388608;        // value bf16   (4M)
  u16* wqb  = ws + 12582912;       // Wq bf16      (1M)
  u16* wkb  = ws + 13631488;
  u16* wvb  = ws + 14680064;
  u16* wob  = ws + 15728640;
  u16* qperm = ws + 16777216;      // Q  [b,h,s,64]  (4M)
  u16* kperm = ws + 20971520;      // K  [b,h,s,64]  (4M)
  u16* vtp   = ws + 25165824;      // V^T[b,h,64,s]  (4M)
  u16* aout  = ws + 29360128;      // attn out [b,s,1024] (4M)
  // total: 64 MB of workspace

  convert_kernel<<<8192, 256, 0, stream>>>(q, k, v, Wq, Wk, Wv, Wo, ws);
  qkv_gemm_kernel<<<dim3(32, 8, 3), 512, 0, stream>>>(xq, xk, xv, wqb, wkb, wvb,
                                                      bq, bk, bv, qperm, kperm, vtp);
  attn_kernel<<<512, 256, 0, stream>>>(qperm, kperm, vtp, aout);
  out_gemm_kernel<<<dim3(32, 8), 512, 0, stream>>>(aout, wob, bo, (float*)d_out);
}

// Round 19
// 101.594 us; speedup vs baseline: 1.0447x; 1.0447x over previous
//
#include <hip/hip_runtime.h>

typedef unsigned short u16;
typedef unsigned int u32;
typedef __attribute__((ext_vector_type(8))) __bf16 bf16x8;
typedef __attribute__((ext_vector_type(4))) float f32x4;
typedef __attribute__((ext_vector_type(16))) float f32x16;
typedef __attribute__((ext_vector_type(4))) u32 u32x4;

#define LOG2E 1.44269504088896340736f

__device__ __forceinline__ u16 f2bf(float f) {
  u32 u = __builtin_bit_cast(u32, f);
  u += 0x7fffu + ((u >> 16) & 1u);
  return (u16)(u >> 16);
}

__device__ __forceinline__ void async_copy16(const u16* g, u16* l) {
  __builtin_amdgcn_global_load_lds((const __attribute__((address_space(1))) void*)g,
                                   (__attribute__((address_space(3))) void*)l,
                                   16, 0, 0);
}

__device__ __forceinline__ bf16x8 ldb8(const u16* p) {
  return *(const bf16x8*)p;
}

__device__ __forceinline__ u32 cvtpk(float lo, float hi) {
  u32 w;
  asm("v_cvt_pk_bf16_f32 %0, %1, %2" : "=v"(w) : "v"(lo), "v"(hi));
  return w;
}

// ---------------------------------------------------------------------------
// Kernel 1: fused f32 -> bf16 conversion (memory floor ~15 µs).
// ---------------------------------------------------------------------------
__global__ __launch_bounds__(256) void convert_kernel(
    const float* __restrict__ q, const float* __restrict__ k, const float* __restrict__ v,
    const float* __restrict__ wq, const float* __restrict__ wk,
    const float* __restrict__ wv, const float* __restrict__ wo,
    u16* __restrict__ out)
{
  size_t t = (size_t)blockIdx.x * 256 + threadIdx.x;  // 0 .. 2M-1
  size_t e = t * 8;
  const float* src;
  size_t off;
  if (e < 12582912) {            // 3 x 4M qkv region
    int which = (int)(e >> 22);
    src = (which == 0) ? q : ((which == 1) ? k : v);
    off = e & 4194303;
  } else {                        // 4 x 1M weight region
    size_t r = e - 12582912;
    int which = (int)(r >> 20);
    src = (which == 0) ? wq : ((which == 1) ? wk : ((which == 2) ? wv : wo));
    off = r & 1048575;
  }
  float4 f0 = *(const float4*)(src + off);
  float4 f1 = *(const float4*)(src + off + 4);
  ushort4 u0, u1;
  u0.x = f2bf(f0.x); u0.y = f2bf(f0.y); u0.z = f2bf(f0.z); u0.w = f2bf(f0.w);
  u1.x = f2bf(f1.x); u1.y = f2bf(f1.y); u1.z = f2bf(f1.z); u1.w = f2bf(f1.w);
  *(ushort4*)(out + e) = u0;
  *(ushort4*)(out + e + 4) = u1;
}

// ---------------------------------------------------------------------------
// R16 GEMM core: 128x128 block, 8 waves (2x4), wave tile 64x32, BK=64,
// 64 KB LDS -> 2 blocks/CU, 16 waves/CU. 16x16x32 MFMA, 0-conflict swizzle
// (slot=cc^(row&7), pre-swizzled DMA source + same XOR on ds_read), T3
// schedule (STAGE(t+1) top, compute, __syncthreads bottom).
// ---------------------------------------------------------------------------
template <int MODE>
__device__ __forceinline__ void gemm128x128w8(
    const u16* __restrict__ A, const u16* __restrict__ W,
    const float* __restrict__ bias, void* __restrict__ out,
    float scale, u16* As, u16* Bs)
{
  const int tid = threadIdx.x;
  const int wid = tid >> 6, lane = tid & 63;
  const int g = lane >> 4, l16 = lane & 15;
  const int wr = wid >> 2, wc = wid & 3;          // 2 x 4 wave grid
  const int brow = blockIdx.x * 128, bcol = blockIdx.y * 128;

  f32x4 acc[4][2] = {};
  const u16* Ab = A + (size_t)brow * 1024;
  const u16* Wb = W + (size_t)bcol * 1024;

  auto STAGE = [&](int buf, int kt2) {
    const int k0 = kt2 * 64;
    u16* Ad = As + buf * 8192;
    u16* Bd = Bs + buf * 8192;
#pragma unroll
    for (int i = 0; i < 2; ++i) {
      const int chunk = i * 512 + tid;
      const int row = chunk >> 3, cc = chunk & 7;
      const int sc = (cc ^ (row & 7)) * 8;
      const int lbase = (i * 512 + wid * 64) * 8;  // elems; HW adds lane*16B
      async_copy16(Ab + (size_t)row * 1024 + k0 + sc, Ad + lbase);
      async_copy16(Wb + (size_t)row * 1024 + k0 + sc, Bd + lbase);
    }
  };

  STAGE(0, 0);
  __syncthreads();

  for (int kt = 0; kt < 16; ++kt) {
    if (kt < 15) STAGE((kt + 1) & 1, kt + 1);   // prefetch next tile (async)

    const u16* Ac = As + (kt & 1) * 8192;
    const u16* Bc = Bs + (kt & 1) * 8192;

    bf16x8 a[4][2], b[2][2];
#pragma unroll
    for (int m = 0; m < 4; ++m) {
      const int row = wr * 64 + m * 16 + l16;
#pragma unroll
      for (int kk = 0; kk < 2; ++kk)
        a[m][kk] = ldb8(Ac + row * 64 + (((kk * 4 + g) ^ (row & 7)) * 8));
    }
#pragma unroll
    for (int n = 0; n < 2; ++n) {
      const int row = wc * 32 + n * 16 + l16;
#pragma unroll
      for (int kk = 0; kk < 2; ++kk)
        b[n][kk] = ldb8(Bc + row * 64 + (((kk * 4 + g) ^ (row & 7)) * 8));
    }
#pragma unroll
    for (int m = 0; m < 4; ++m)
#pragma unroll
      for (int n = 0; n < 2; ++n) {
        acc[m][n] = __builtin_amdgcn_mfma_f32_16x16x32_bf16(a[m][0], b[n][0], acc[m][n], 0, 0, 0);
        acc[m][n] = __builtin_amdgcn_mfma_f32_16x16x32_bf16(a[m][1], b[n][1], acc[m][n], 0, 0, 0);
      }

    __syncthreads();
  }

  // epilogue
#pragma unroll
  for (int m = 0; m < 4; ++m) {
    const int mg = brow + wr * 64 + m * 16 + g * 4;  // + j
#pragma unroll
    for (int n = 0; n < 2; ++n) {
      const int cg = bcol + wc * 32 + n * 16 + l16;
      const float bb = bias[cg];
      if constexpr (MODE == 0) {
        const int h = cg >> 6, d = cg & 63;
#pragma unroll
        for (int j = 0; j < 4; ++j) {
          const int row = mg + j;
          const int bb_ = row >> 11, s = row & 2047;
          ((u16*)out)[(((size_t)(bb_ * 16 + h) * 2048 + s) << 6) + d] =
              f2bf((acc[m][n][j] + bb) * scale);
        }
      } else if constexpr (MODE == 1) {
        const int h = cg >> 6, d = cg & 63;
        const int bb_ = mg >> 11, s0 = mg & 2047;
        ushort4 pk;
        pk.x = f2bf(acc[m][n][0] + bb);
        pk.y = f2bf(acc[m][n][1] + bb);
        pk.z = f2bf(acc[m][n][2] + bb);
        pk.w = f2bf(acc[m][n][3] + bb);
        *(ushort4*)((u16*)out + ((size_t)(bb_ * 16 + h) * 64 + d) * 2048 + s0) = pk;
      } else {
#pragma unroll
        for (int j = 0; j < 4; ++j) {
          const int row = mg + j;
          ((float*)out)[(size_t)row * 1024 + cg] = acc[m][n][j] + bb;
        }
      }
    }
  }
}

__global__ __launch_bounds__(512) void qkv_gemm_kernel(
    const u16* __restrict__ xq, const u16* __restrict__ xk, const u16* __restrict__ xv,
    const u16* __restrict__ wq, const u16* __restrict__ wk, const u16* __restrict__ wv,
    const float* __restrict__ bq, const float* __restrict__ bk, const float* __restrict__ bv,
    u16* __restrict__ oq, u16* __restrict__ ok, u16* __restrict__ ov)
{
  __shared__ u16 As[2][8192];
  __shared__ u16 Bs[2][8192];
  const int z = blockIdx.z;
  // Q pre-scaled by 1/sqrt(64) * log2(e): attention then uses p = exp2(s) directly.
  if (z == 0)      gemm128x128w8<0>(xq, wq, bq, oq, 0.125f * LOG2E, &As[0][0], &Bs[0][0]);
  else if (z == 1) gemm128x128w8<0>(xk, wk, bk, ok, 1.0f, &As[0][0], &Bs[0][0]);    // K
  else             gemm128x128w8<1>(xv, wv, bv, ov, 1.0f, &As[0][0], &Bs[0][0]);    // V transposed
}

__global__ __launch_bounds__(512) void out_gemm_kernel(
    const u16* __restrict__ a, const u16* __restrict__ w,
    const float* __restrict__ bias, float* __restrict__ o)
{
  __shared__ u16 As[2][8192];
  __shared__ u16 Bs[2][8192];
  gemm128x128w8<2>(a, w, bias, o, 1.0f, &As[0][0], &Bs[0][0]);
}

// ---------------------------------------------------------------------------
// Kernel 3 (R17, global best): flash attention with TWO q-sets per wave
// (64 q-rows). K/V fragments shared between q-sets (16 ds_read/wave/round)
// while MFMA doubles to 40/wave/round as 2 INDEPENDENT chains -> 2x ILP on
// the QK->exp->pack->PV critical path and 2x FLOP per LDS byte. 8 waves
// (4 q-owners x 2 KV-parity groups), grid 256 (1 block/CU, 2 waves/SIMD,
// launch_bounds(512,2)). Fixed-max softmax -> exact additive combine across
// parity (lane-major publish = conflict-free). SB[0..3]=K bufs, [4..7]=V.
// XCD remap: 256 blocks -> 4 heads/XCD.
// ---------------------------------------------------------------------------
__global__ __launch_bounds__(512, 2) void attn_kernel(
    const u16* __restrict__ qp, const u16* __restrict__ kp,
    const u16* __restrict__ vt, u16* __restrict__ ao)
{
  __shared__ u16 SB[8][4096];   // [0..3]=K tile bufs, [4..7]=V tile bufs, 64 KB

  const int tid = threadIdx.x;
  const int wid = tid >> 6, lane = tid & 63;
  const int u = lane >> 5, l32 = lane & 31;
  const int wsub = wid & 3, g2 = wid >> 2;   // q-owner / KV parity group

  // XCD-chunked remap: 256 blocks, 8 XCDs -> each XCD owns 4 whole heads.
  int bid = (int)blockIdx.x;
  bid = (bid & 7) * 32 + (bid >> 3);
  const int bh = bid >> 3;                   // b*16 + h
  const int q0 = (bid & 7) * 256 + wsub * 64;

  const u16* Q = qp + ((size_t)bh * 2048 + q0) * 64;
  const u16* K = kp + (size_t)bh * 2048 * 64;
  const u16* V = vt + (size_t)bh * 64 * 2048;

  // Q as B-fragments, two q-sets: col = q = qs*32 + l32
  bf16x8 aq[2][4];
#pragma unroll
  for (int qs = 0; qs < 2; ++qs)
#pragma unroll
    for (int st = 0; st < 4; ++st)
      aq[qs][st] = ldb8(Q + (qs * 32 + l32) * 64 + st * 16 + u * 8);

  f32x16 outa[2][2] = {};   // [qs][nb] C[q_row][d=nb*32+l32]
  f32x16 outsum[2] = {};    // [qs] running row-sum (denominator)
  f32x16 zf16 = {};

  const __bf16 one_bf = (__bf16)1.0f;
  bf16x8 ones = {one_bf, one_bf, one_bf, one_bf, one_bf, one_bf, one_bf, one_bf};

  // stage ONE tile (512 threads, 1 K-load + 1 V-load per thread).
  auto STAGE1 = [&](int buf, int kb) {
    const int half = tid >> 8, row = (tid & 255) >> 2, slot = tid & 3;
    const int sc = (slot ^ ((row >> 1) & 3)) * 8;
    async_copy16(K + (size_t)(kb + row) * 64 + half * 32 + sc, &SB[buf][wid * 512]);
    async_copy16(V + (size_t)row * 2048 + kb + half * 32 + sc, &SB[4 + buf][wid * 512]);
  };

  STAGE1(0, 0);      // tile 0
  STAGE1(1, 64);     // tile 1

  for (int T = 0; T < 16; ++T) {
    __syncthreads();   // pair T ready (staged one full round ago); pair T+1 bufs free
    if (T < 15) {
      STAGE1((2 * T + 2) & 3, (2 * T + 2) * 64);
      STAGE1((2 * T + 3) & 3, (2 * T + 3) * 64);
    }

    const int kt = 2 * T + g2;   // group 0: even tiles, group 1: odd tiles
    const u16* Kb = &SB[kt & 3][0];
    const u16* Vb = &SB[4 + (kt & 3)][0];

    // Swapped QK^T for BOTH q-sets, sharing each K fragment.
    f32x16 s[2][2];   // [qs][half]
    __builtin_amdgcn_s_setprio(1);
#pragma unroll
    for (int half = 0; half < 2; ++half) {
      const int krow = half * 32 + l32;
#pragma unroll
      for (int st = 0; st < 4; ++st) {
        const bf16x8 kf = ldb8(Kb + (st >> 1) * 2048 + krow * 32 +
                               ((((st & 1) * 2 + u) ^ ((krow >> 1) & 3)) * 8));
        s[0][half] = __builtin_amdgcn_mfma_f32_32x32x16_bf16(
            kf, aq[0][st], (st == 0) ? zf16 : s[0][half], 0, 0, 0);
        s[1][half] = __builtin_amdgcn_mfma_f32_32x32x16_bf16(
            kf, aq[1][st], (st == 0) ? zf16 : s[1][half], 0, 0, 0);
      }
    }
    __builtin_amdgcn_s_setprio(0);

    // p = exp2(s); pack adjacent-k pairs to bf16x2 words (per q-set chain)
    u32 Wd[2][2][8];
#pragma unroll
    for (int qs = 0; qs < 2; ++qs)
#pragma unroll
      for (int half = 0; half < 2; ++half)
#pragma unroll
        for (int p = 0; p < 8; ++p) {
          const float p0 = __builtin_amdgcn_exp2f(s[qs][half][2 * p]);
          const float p1 = __builtin_amdgcn_exp2f(s[qs][half][2 * p + 1]);
          Wd[qs][half][p] = cvtpk(p0, p1);
        }

    // PV: 4 k-steps of 16; V fragment shared between the two q-set chains.
#pragma unroll
    for (int t = 0; t < 4; ++t) {
      bf16x8 paf[2];
#pragma unroll
      for (int qs = 0; qs < 2; ++qs) {
        u32 c0 = Wd[qs][t >> 1][(t & 1) * 4 + 0];
        u32 c1 = Wd[qs][t >> 1][(t & 1) * 4 + 1];
        u32 c2 = Wd[qs][t >> 1][(t & 1) * 4 + 2];
        u32 c3 = Wd[qs][t >> 1][(t & 1) * 4 + 3];
        asm volatile("v_permlane32_swap_b32 %0, %1" : "+v"(c0), "+v"(c2));
        asm volatile("v_permlane32_swap_b32 %0, %1" : "+v"(c1), "+v"(c3));
        u32x4 wv = {c0, c1, c2, c3};
        paf[qs] = __builtin_bit_cast(bf16x8, wv);
      }
      __builtin_amdgcn_s_setprio(1);
      outsum[0] = __builtin_amdgcn_mfma_f32_32x32x16_bf16(paf[0], ones, outsum[0], 0, 0, 0);
      outsum[1] = __builtin_amdgcn_mfma_f32_32x32x16_bf16(paf[1], ones, outsum[1], 0, 0, 0);
#pragma unroll
      for (int nb = 0; nb < 2; ++nb) {
        const int dv = nb * 32 + l32;
        const bf16x8 vf = ldb8(Vb + (t >> 1) * 2048 + dv * 32 +
                               ((((t & 1) * 2 + u) ^ ((dv >> 1) & 3)) * 8));
        outa[0][nb] = __builtin_amdgcn_mfma_f32_32x32x16_bf16(paf[0], vf, outa[0][nb], 0, 0, 0);
        outa[1][nb] = __builtin_amdgcn_mfma_f32_32x32x16_bf16(paf[1], vf, outa[1][nb], 0, 0, 0);
      }
      __builtin_amdgcn_s_setprio(0);
    }
  }

  // ---- exact combine across parity groups (lane-major, conflict-free) ----
  __syncthreads();
  float* ex = (float*)&SB[0][0];    // 16384 floats = 64 KB
  if (wid >= 4) {
#pragma unroll
    for (int qs = 0; qs < 2; ++qs)
#pragma unroll
      for (int nb = 0; nb < 2; ++nb)
#pragma unroll
        for (int r = 0; r < 16; ++r)
          ex[(((wid - 4) * 64 + qs * 32 + nb * 16 + r)) * 64 + lane] = outa[qs][nb][r];
  }
  __syncthreads();
  if (wid < 4) {
#pragma unroll
    for (int qs = 0; qs < 2; ++qs)
#pragma unroll
      for (int nb = 0; nb < 2; ++nb)
#pragma unroll
        for (int r = 0; r < 16; ++r)
          outa[qs][nb][r] += ex[((wid * 64 + qs * 32 + nb * 16 + r)) * 64 + lane];
  }
  __syncthreads();
  if (wid >= 4) {
#pragma unroll
    for (int qs = 0; qs < 2; ++qs)
#pragma unroll
      for (int r = 0; r < 16; ++r)
        ex[(((wid - 4) * 32 + qs * 16 + r)) * 64 + lane] = outsum[qs][r];
  }
  __syncthreads();
  if (wid < 4) {
    const int b = bh >> 4, h = bh & 15;
#pragma unroll
    for (int qs = 0; qs < 2; ++qs) {
#pragma unroll
      for (int r = 0; r < 16; ++r) {
        const float l = outsum[qs][r] + ex[((wid * 32 + qs * 16 + r)) * 64 + lane];
        const float inv = 1.0f / l;
        const int srow = q0 + qs * 32 + (r & 3) + 8 * (r >> 2) + 4 * u;
#pragma unroll
        for (int nb = 0; nb < 2; ++nb) {
          ao[((size_t)b * 2048 + srow) * 1024 + h * 64 + nb * 32 + l32] =
              __builtin_bit_cast(u16, (__bf16)(outa[qs][nb][r] * inv));
        }
      }
    }
  }
}

// ---------------------------------------------------------------------------
extern "C" void kernel_launch(void* const* d_in, const int* in_sizes, int n_in,
                              void* d_out, int out_size, void* d_ws, size_t ws_size,
                              hipStream_t stream) {
  const float* q  = (const float*)d_in[0];
  const float* k  = (const float*)d_in[1];
  const float* v  = (const float*)d_in[2];
  const float* Wq = (const float*)d_in[3];
  const float* bq = (const float*)d_in[4];
  const float* Wk = (const float*)d_in[5];
  const float* bk = (const float*)d_in[6];
  const float* Wv = (const float*)d_in[7];
  const float* bv = (const float*)d_in[8];
  const float* Wo = (const float*)d_in[9];
  const float* bo = (const float*)d_in[10];

  u16* ws = (u16*)d_ws;
  u16* xq   = ws;                  // query bf16   (4M)
  u16* xk   = ws + 4194304;        // key bf16     (4M)
  u16* xv   = ws + 8388608;        // value bf16   (4M)
  u16* wqb  = ws + 12582912;       // Wq bf16      (1M)
  u16* wkb  = ws + 13631488;
  u16* wvb  = ws + 14680064;
  u16* wob  = ws + 15728640;
  u16* qperm = ws + 16777216;      // Q  [b,h,s,64]  (4M)
  u16* kperm = ws + 20971520;      // K  [b,h,s,64]  (4M)
  u16* vtp   = ws + 25165824;      // V^T[b,h,64,s]  (4M)
  u16* aout  = ws + 29360128;      // attn out [b,s,1024] (4M)
  // total: 64 MB of workspace

  convert_kernel<<<8192, 256, 0, stream>>>(q, k, v, Wq, Wk, Wv, Wo, ws);
  qkv_gemm_kernel<<<dim3(32, 8, 3), 512, 0, stream>>>(xq, xk, xv, wqb, wkb, wvb,
                                                      bq, bk, bv, qperm, kperm, vtp);
  attn_kernel<<<256, 512, 0, stream>>>(qperm, kperm, vtp, aout);
  out_gemm_kernel<<<dim3(32, 8), 512, 0, stream>>>(aout, wob, bo, (float*)d_out);
}